// Round 1
// baseline (748.938 us; speedup 1.0000x reference)
//
#include <hip/hip_runtime.h>
#include <hip/hip_bf16.h>
#include <cstdint>

#define DI __device__ __forceinline__

typedef unsigned short ushort_t;
using u16x8  = __attribute__((ext_vector_type(8))) unsigned short;
using bf16x8 = __attribute__((ext_vector_type(8))) __bf16;
using f32x4  = __attribute__((ext_vector_type(4))) float;

typedef const __attribute__((address_space(1))) void GVOID;
typedef __attribute__((address_space(3))) void LVOID;

enum { BB = 16384, DIN = 512, H0 = 1024, H1 = 1024, DOUT = 64, NE = 8, GH = 128 };

DI void async_ld16(const void* g, void* l) {
    __builtin_amdgcn_global_load_lds((GVOID*)g, (LVOID*)l, 16, 0, 0);
}

DI unsigned short f2bf(float f) {  // RTNE f32 -> bf16 bits
    union { float f; unsigned u; } v; v.f = f;
    unsigned r = v.u + 0x7FFF + ((v.u >> 16) & 1);
    return (unsigned short)(r >> 16);
}
DI float bf2f(unsigned short u) { return __uint_as_float(((unsigned)u) << 16); }
DI f32x4 zero4() { f32x4 v = {0.f, 0.f, 0.f, 0.f}; return v; }

// ---------------------------------------------------------------------------
// f32 -> bf16 convert (inputs), 8 elems/thread, exact grid
// ---------------------------------------------------------------------------
__global__ void f32_to_bf16_vec(const float* __restrict__ in, ushort_t* __restrict__ out) {
    const int i = (blockIdx.x * 256 + threadIdx.x) * 8;
    const float4 a = *(const float4*)&in[i];
    const float4 b = *(const float4*)&in[i + 4];
    u16x8 o;
    o[0] = f2bf(a.x); o[1] = f2bf(a.y); o[2] = f2bf(a.z); o[3] = f2bf(a.w);
    o[4] = f2bf(b.x); o[5] = f2bf(b.y); o[6] = f2bf(b.z); o[7] = f2bf(b.w);
    *(u16x8*)&out[i] = o;
}

// ---------------------------------------------------------------------------
// W [K][N] f32 -> Wt [N][K] bf16, 64x64 tiles via LDS (pad 69 vs bank conflicts)
// ---------------------------------------------------------------------------
__global__ void transpose_convert(const float* __restrict__ W, ushort_t* __restrict__ Wt,
                                  int K, int N) {
    __shared__ float t[64][69];
    const int tid = threadIdx.x;
    const int k0 = blockIdx.x * 64, n0 = blockIdx.y * 64;
    for (int rr = tid >> 4; rr < 64; rr += 16) {
        const int c = (tid & 15) * 4;
        const float4 v = *(const float4*)&W[(size_t)(k0 + rr) * N + n0 + c];
        t[rr][c] = v.x; t[rr][c + 1] = v.y; t[rr][c + 2] = v.z; t[rr][c + 3] = v.w;
    }
    __syncthreads();
    for (int nn = tid >> 3; nn < 64; nn += 32) {
        const int k8 = (tid & 7) * 8;
        u16x8 o;
#pragma unroll
        for (int j = 0; j < 8; ++j) o[j] = f2bf(t[k8 + j][nn]);
        *(u16x8*)&Wt[(size_t)(n0 + nn) * K + k0 + k8] = o;
    }
}

// ---------------------------------------------------------------------------
// gate layer 3 + softmax: h2 [B,128] bf16 @ gw3 [128,8] f32 + gb3 -> softmax -> g [B,8] f32
// ---------------------------------------------------------------------------
__global__ void gate3_softmax(const ushort_t* __restrict__ h2, const float* __restrict__ gw3,
                              const float* __restrict__ gb3, float* __restrict__ g) {
    __shared__ float w[GH * NE];
    const int tid = threadIdx.x;
    for (int i = tid; i < GH * NE; i += 256) w[i] = gw3[i];
    __syncthreads();
    const int b = blockIdx.x * 256 + tid;
    float lg[NE];
#pragma unroll
    for (int e = 0; e < NE; ++e) lg[e] = gb3[e];
    const ushort_t* row = h2 + (size_t)b * GH;
    for (int h8 = 0; h8 < GH; h8 += 8) {
        const u16x8 v = *(const u16x8*)&row[h8];
#pragma unroll
        for (int j = 0; j < 8; ++j) {
            const float xv = bf2f(v[j]);
#pragma unroll
            for (int e = 0; e < NE; ++e) lg[e] += xv * w[(h8 + j) * NE + e];
        }
    }
    float mx = lg[0];
#pragma unroll
    for (int e = 1; e < NE; ++e) mx = fmaxf(mx, lg[e]);
    float s = 0.f;
#pragma unroll
    for (int e = 0; e < NE; ++e) { lg[e] = __expf(lg[e] - mx); s += lg[e]; }
    const float inv = 1.f / s;
#pragma unroll
    for (int e = 0; e < NE; ++e) g[(size_t)b * NE + e] = lg[e] * inv;
}

// ---------------------------------------------------------------------------
// Fused (MoE-)GEMM.  out[b,n] = act( sum_k A[b,k] * Wt[n,k] + bias )
//   GATED:  A[b, e*H+d] = g[b,e] * X[b,d]  (implemented by per-expert partial
//           accumulator folded with g at expert boundaries), bias = sum_e g[b,e]*bias[e,n]
//   else:   A = X [B,K], bias = bias[n]
// 128x(BN) tile, BK=64, 4 waves (2x2), 16x16x32 bf16 MFMA, global_load_lds staging.
// ---------------------------------------------------------------------------
template <int BN, int TPE, int ACT, bool GATED, bool OUTF32>
__global__ __launch_bounds__(256, 2) void moe_gemm(
    const ushort_t* __restrict__ X, const ushort_t* __restrict__ Wt,
    const float* __restrict__ gvec, const float* __restrict__ bias,
    void* __restrict__ outv, int M, int N, int K) {
    constexpr int BM = 128, BK = 64;
    constexpr int NF = BN / 32;  // n-frags per wave
    const int tid = threadIdx.x;
    const int wid = tid >> 6, lane = tid & 63;
    const int lr = lane & 15, lk = lane >> 4;
    const int bm0 = blockIdx.x * BM;
    const int bn0 = blockIdx.y * BN;
    const int wm0 = (wid >> 1) * 64;
    const int wn0 = (wid & 1) * (BN / 2);

    __shared__ short lds_a[BM * BK];
    __shared__ short lds_b[BN * BK];
    __shared__ float lds_g[BM * 8];
    __shared__ float lds_bias[8 * BN];

    if constexpr (GATED) {
        ((f32x4*)lds_g)[tid] = ((const f32x4*)(gvec + (size_t)bm0 * 8))[tid];
        for (int i = tid; i < 8 * BN; i += 256) {
            const int e = i / BN, n = i - e * BN;
            lds_bias[i] = bias[(size_t)e * N + bn0 + n];
        }
    }

    f32x4 acc_t[4][NF], acc_p[4][NF];
#pragma unroll
    for (int m = 0; m < 4; ++m)
#pragma unroll
        for (int n = 0; n < NF; ++n) { acc_t[m][n] = zero4(); acc_p[m][n] = zero4(); }

    f32x4(&amain)[4][NF] = GATED ? acc_p : acc_t;  // MFMA target

    const int xstride = (TPE > 0) ? TPE * BK : K;  // X row length (elements)
    const int NT = K / BK;
    for (int kt = 0; kt < NT; ++kt) {
        // ---- stage A and B tiles (rows of 128B) via global_load_lds ----
        int kcolA;
        if constexpr (TPE > 0) kcolA = (kt % TPE) * BK; else kcolA = kt * BK;
        {
            const ushort_t* abase = X + (size_t)bm0 * xstride + kcolA;
#pragma unroll
            for (int c = wid; c < (BM * BK * 2) / 1024; c += 4) {
                const int off = c * 1024 + lane * 16;
                const int r = off >> 7, cb = off & 127;
                async_ld16((const char*)abase + (size_t)r * (xstride * 2) + cb,
                           (char*)lds_a + c * 1024);
            }
            const ushort_t* bbase = Wt + (size_t)bn0 * K + kt * BK;
#pragma unroll
            for (int c = wid; c < (BN * BK * 2) / 1024; c += 4) {
                const int off = c * 1024 + lane * 16;
                const int r = off >> 7, cb = off & 127;
                async_ld16((const char*)bbase + (size_t)r * ((size_t)K * 2) + cb,
                           (char*)lds_b + c * 1024);
            }
        }
        __syncthreads();  // compiler drains vmcnt(0) here -> LDS tiles valid

        // ---- compute: 2 k-steps of 32, 4x(NF) frags ----
        bf16x8 af[2][4], bfr[2][NF];
#pragma unroll
        for (int k2 = 0; k2 < 2; ++k2) {
#pragma unroll
            for (int m = 0; m < 4; ++m)
                af[k2][m] = *(const bf16x8*)&lds_a[(wm0 + m * 16 + lr) * BK + k2 * 32 + lk * 8];
#pragma unroll
            for (int n = 0; n < NF; ++n)
                bfr[k2][n] = *(const bf16x8*)&lds_b[(wn0 + n * 16 + lr) * BK + k2 * 32 + lk * 8];
        }
#pragma unroll
        for (int m = 0; m < 4; ++m)
#pragma unroll
            for (int n = 0; n < NF; ++n) {
                amain[m][n] = __builtin_amdgcn_mfma_f32_16x16x32_bf16(af[0][m], bfr[0][n], amain[m][n], 0, 0, 0);
                amain[m][n] = __builtin_amdgcn_mfma_f32_16x16x32_bf16(af[1][m], bfr[1][n], amain[m][n], 0, 0, 0);
            }

        if constexpr (TPE > 0) {  // expert boundary: fold partial with gate weight
            if ((kt + 1) % TPE == 0) {
                const int e = kt / TPE;
#pragma unroll
                for (int m = 0; m < 4; ++m)
#pragma unroll
                    for (int j = 0; j < 4; ++j) {
                        const float gw = lds_g[(wm0 + m * 16 + lk * 4 + j) * 8 + e];
#pragma unroll
                        for (int n = 0; n < NF; ++n) {
                            acc_t[m][n][j] += gw * acc_p[m][n][j];
                            acc_p[m][n][j] = 0.f;
                        }
                    }
            }
        }
        __syncthreads();  // all waves done reading LDS before next overwrite
    }

    // ---- epilogue: bias + activation + store ----
#pragma unroll
    for (int m = 0; m < 4; ++m)
#pragma unroll
        for (int n = 0; n < NF; ++n)
#pragma unroll
            for (int j = 0; j < 4; ++j) {
                const int row = wm0 + m * 16 + lk * 4 + j;
                const int col = wn0 + n * 16 + lr;
                float v = acc_t[m][n][j];
                if constexpr (GATED) {
                    float bs = 0.f;
#pragma unroll
                    for (int e = 0; e < 8; ++e) bs += lds_g[row * 8 + e] * lds_bias[e * BN + col];
                    v += bs;
                } else {
                    v += bias[bn0 + col];
                }
                if constexpr (ACT == 0) v = fmaxf(v, 0.f);
                else if constexpr (ACT == 1) v = tanhf(v);
                const size_t oidx = (size_t)(bm0 + row) * N + (bn0 + col);
                if constexpr (OUTF32) ((float*)outv)[oidx] = v;
                else ((ushort_t*)outv)[oidx] = f2bf(v);
            }
}

// ---------------------------------------------------------------------------
extern "C" void kernel_launch(void* const* d_in, const int* in_sizes, int n_in,
                              void* d_out, int out_size, void* d_ws, size_t ws_size,
                              hipStream_t stream) {
    const float* inputs = (const float*)d_in[0];
    const float* gw1 = (const float*)d_in[1];
    const float* gb1 = (const float*)d_in[2];
    const float* gw2 = (const float*)d_in[3];
    const float* gb2 = (const float*)d_in[4];
    const float* gw3 = (const float*)d_in[5];
    const float* gb3 = (const float*)d_in[6];
    const float* w0 = (const float*)d_in[7];
    const float* b0 = (const float*)d_in[8];
    const float* w1 = (const float*)d_in[9];
    const float* b1 = (const float*)d_in[10];
    const float* w2 = (const float*)d_in[11];
    const float* b2 = (const float*)d_in[12];

    char* ws = (char*)d_ws;
    size_t off = 0;
    auto alloc = [&](size_t bytes) -> char* {
        char* p = ws + off;
        off += (bytes + 255) & ~(size_t)255;
        return p;
    };
    ushort_t* x0b = (ushort_t*)alloc((size_t)BB * DIN * 2);        // 16.8 MB
    ushort_t* W0t = (ushort_t*)alloc((size_t)(NE * DIN) * H0 * 2); // 8.4 MB  [H0][E*DIN]
    ushort_t* W1t = (ushort_t*)alloc((size_t)(NE * H0) * H1 * 2);  // 16.8 MB [H1][E*H0]
    ushort_t* W2t = (ushort_t*)alloc((size_t)(NE * H1) * DOUT * 2);// 1.05 MB [DOUT][E*H1]
    ushort_t* G1t = (ushort_t*)alloc((size_t)DIN * GH * 2);
    ushort_t* G2t = (ushort_t*)alloc((size_t)GH * GH * 2);
    ushort_t* h1b = (ushort_t*)alloc((size_t)BB * GH * 2);
    ushort_t* h2b = (ushort_t*)alloc((size_t)BB * GH * 2);
    float*    gv  = (float*)alloc((size_t)BB * NE * 4);
    ushort_t* x1b = (ushort_t*)alloc((size_t)BB * H0 * 2);
    ushort_t* x2b = (ushort_t*)alloc((size_t)BB * H1 * 2);
    (void)ws_size; (void)in_sizes; (void)n_in; (void)out_size;

    // convert + transpose weights/inputs to bf16
    f32_to_bf16_vec<<<dim3((BB * DIN) / (256 * 8)), 256, 0, stream>>>(inputs, x0b);
    transpose_convert<<<dim3((NE * DIN) / 64, H0 / 64), 256, 0, stream>>>(w0, W0t, NE * DIN, H0);
    transpose_convert<<<dim3((NE * H0) / 64, H1 / 64), 256, 0, stream>>>(w1, W1t, NE * H0, H1);
    transpose_convert<<<dim3((NE * H1) / 64, DOUT / 64), 256, 0, stream>>>(w2, W2t, NE * H1, DOUT);
    transpose_convert<<<dim3(DIN / 64, GH / 64), 256, 0, stream>>>(gw1, G1t, DIN, GH);
    transpose_convert<<<dim3(GH / 64, GH / 64), 256, 0, stream>>>(gw2, G2t, GH, GH);

    // gate MLP
    moe_gemm<128, 0, 0, false, false><<<dim3(BB / 128, GH / 128), 256, 0, stream>>>(
        x0b, G1t, nullptr, gb1, h1b, BB, GH, DIN);
    moe_gemm<128, 0, 0, false, false><<<dim3(BB / 128, GH / 128), 256, 0, stream>>>(
        h1b, G2t, nullptr, gb2, h2b, BB, GH, GH);
    gate3_softmax<<<dim3(BB / 256), 256, 0, stream>>>(h2b, gw3, gb3, gv);

    // expert layers (gated)
    moe_gemm<128, 8, 0, true, false><<<dim3(BB / 128, H0 / 128), 256, 0, stream>>>(
        x0b, W0t, gv, b0, x1b, BB, H0, NE * DIN);
    moe_gemm<128, 16, 0, true, false><<<dim3(BB / 128, H1 / 128), 256, 0, stream>>>(
        x1b, W1t, gv, b1, x2b, BB, H1, NE * H0);
    moe_gemm<64, 16, 1, true, true><<<dim3(BB / 128, DOUT / 64), 256, 0, stream>>>(
        x2b, W2t, gv, b2, d_out, BB, DOUT, NE * H1);
}

// Round 2
// 559.779 us; speedup vs baseline: 1.3379x; 1.3379x over previous
//
#include <hip/hip_runtime.h>
#include <hip/hip_bf16.h>
#include <cstdint>

#define DI __device__ __forceinline__

typedef unsigned short ushort_t;
using u16x8  = __attribute__((ext_vector_type(8))) unsigned short;
using bf16x8 = __attribute__((ext_vector_type(8))) __bf16;
using f32x4  = __attribute__((ext_vector_type(4))) float;

typedef const __attribute__((address_space(1))) void GVOID;
typedef __attribute__((address_space(3))) void LVOID;

enum { BB = 16384, DIN = 512, H0 = 1024, H1 = 1024, DOUT = 64, NE = 8, GH = 128 };

DI void async_ld16(const void* g, void* l) {
    __builtin_amdgcn_global_load_lds((GVOID*)g, (LVOID*)l, 16, 0, 0);
}

DI unsigned short f2bf(float f) {  // RTNE f32 -> bf16 bits
    union { float f; unsigned u; } v; v.f = f;
    unsigned r = v.u + 0x7FFF + ((v.u >> 16) & 1);
    return (unsigned short)(r >> 16);
}
DI float bf2f(unsigned short u) { return __uint_as_float(((unsigned)u) << 16); }
DI f32x4 zero4() { f32x4 v = {0.f, 0.f, 0.f, 0.f}; return v; }

#define FENCE() asm volatile("" ::: "memory")
#define BARRIER() do { __builtin_amdgcn_s_barrier(); asm volatile("" ::: "memory"); } while (0)

// ---------------------------------------------------------------------------
// f32 -> bf16 convert (inputs), 8 elems/thread, exact grid
// ---------------------------------------------------------------------------
__global__ void f32_to_bf16_vec(const float* __restrict__ in, ushort_t* __restrict__ out) {
    const int i = (blockIdx.x * 256 + threadIdx.x) * 8;
    const float4 a = *(const float4*)&in[i];
    const float4 b = *(const float4*)&in[i + 4];
    u16x8 o;
    o[0] = f2bf(a.x); o[1] = f2bf(a.y); o[2] = f2bf(a.z); o[3] = f2bf(a.w);
    o[4] = f2bf(b.x); o[5] = f2bf(b.y); o[6] = f2bf(b.z); o[7] = f2bf(b.w);
    *(u16x8*)&out[i] = o;
}

// ---------------------------------------------------------------------------
// W [K][N] f32 -> Wt [N][Kext] bf16 (cols [0,K)), 64x64 tiles via LDS
// ---------------------------------------------------------------------------
__global__ void transpose_convert(const float* __restrict__ W, ushort_t* __restrict__ Wt,
                                  int K, int N, int Kext) {
    __shared__ float t[64][69];
    const int tid = threadIdx.x;
    const int k0 = blockIdx.x * 64, n0 = blockIdx.y * 64;
    for (int rr = tid >> 4; rr < 64; rr += 16) {
        const int c = (tid & 15) * 4;
        const float4 v = *(const float4*)&W[(size_t)(k0 + rr) * N + n0 + c];
        t[rr][c] = v.x; t[rr][c + 1] = v.y; t[rr][c + 2] = v.z; t[rr][c + 3] = v.w;
    }
    __syncthreads();
    for (int nn = tid >> 3; nn < 64; nn += 32) {
        const int k8 = (tid & 7) * 8;
        u16x8 o;
#pragma unroll
        for (int j = 0; j < 8; ++j) o[j] = f2bf(t[k8 + j][nn]);
        *(u16x8*)&Wt[(size_t)(n0 + nn) * Kext + k0 + k8] = o;
    }
}

// ---------------------------------------------------------------------------
// Fill appended bias chunk: Wt[n][K + c] = bias[c][n] for c<8, else 0
// ---------------------------------------------------------------------------
__global__ void bias_fill(const float* __restrict__ bias, ushort_t* __restrict__ Wt,
                          int N, int K, int Kext) {
    const int n = blockIdx.x, c = threadIdx.x;  // 128 threads
    Wt[(size_t)n * Kext + K + c] = (c < 8) ? f2bf(bias[(size_t)c * N + n]) : (ushort_t)0;
}

// ---------------------------------------------------------------------------
// gate layer 3 + softmax: h2 [B,128] bf16 @ gw3 [128,8] f32 + gb3 -> softmax
// writes g [B,8] f32  AND  Gx [B,128] bf16 = (g | zeros)
// ---------------------------------------------------------------------------
__global__ void gate3_softmax(const ushort_t* __restrict__ h2, const float* __restrict__ gw3,
                              const float* __restrict__ gb3, float* __restrict__ g,
                              ushort_t* __restrict__ Gx) {
    __shared__ float w[GH * NE];
    const int tid = threadIdx.x;
    for (int i = tid; i < GH * NE; i += 256) w[i] = gw3[i];
    __syncthreads();
    const int b = blockIdx.x * 256 + tid;
    float lg[NE];
#pragma unroll
    for (int e = 0; e < NE; ++e) lg[e] = gb3[e];
    const ushort_t* row = h2 + (size_t)b * GH;
    for (int h8 = 0; h8 < GH; h8 += 8) {
        const u16x8 v = *(const u16x8*)&row[h8];
#pragma unroll
        for (int j = 0; j < 8; ++j) {
            const float xv = bf2f(v[j]);
#pragma unroll
            for (int e = 0; e < NE; ++e) lg[e] += xv * w[(h8 + j) * NE + e];
        }
    }
    float mx = lg[0];
#pragma unroll
    for (int e = 1; e < NE; ++e) mx = fmaxf(mx, lg[e]);
    float s = 0.f;
#pragma unroll
    for (int e = 0; e < NE; ++e) { lg[e] = __expf(lg[e] - mx); s += lg[e]; }
    const float inv = 1.f / s;
#pragma unroll
    for (int e = 0; e < NE; ++e) g[(size_t)b * NE + e] = lg[e] * inv;
    ushort_t* gxr = Gx + (size_t)b * 128;
    u16x8 o;
#pragma unroll
    for (int e = 0; e < NE; ++e) o[e] = f2bf(lg[e] * inv);
    *(u16x8*)gxr = o;
    u16x8 z = {0, 0, 0, 0, 0, 0, 0, 0};
#pragma unroll
    for (int i = 1; i < 16; ++i) *(u16x8*)(gxr + i * 8) = z;
}

// ---------------------------------------------------------------------------
// Pipelined 256x256 MoE GEMM.  out = relu( sum_e g_e (X W_e) + sum_e g_e b_e )
// BK=32, 3-buffer LDS rotation, counted vmcnt(4), per-phase barriers+setprio,
// XOR swizzle (pre-swizzled global src / swizzled LDS read), Horner gate fold,
// bias folded as appended K-chunk (A = Gx, B = Wt cols [K, K+128)).
// 512 threads = 8 waves (2M x 4N), per-wave 128x64 output.
// grid = 256 blocks (M=16384, N=1024), XCD-aware decode.
// ---------------------------------------------------------------------------
template <int TPE, int STRIDEX>
__global__ __launch_bounds__(512, 2) void gemm256(
    const ushort_t* __restrict__ X,     // [M, STRIDEX] bf16
    const ushort_t* __restrict__ Gx,    // [M, 128] bf16
    const ushort_t* __restrict__ Wt,    // [N, Kext] bf16
    const float* __restrict__ gvec,     // [M, 8] f32
    ushort_t* __restrict__ out,         // [M, N] bf16
    int N, int Kext) {
    constexpr int TE = NE * TPE;        // # expert K-tiles (of 32)
    const int NT = Kext >> 5;           // total K-tiles
    const int tid = threadIdx.x;
    const int wid = tid >> 6, l = tid & 63;
    const int wm = wid >> 2, wn = wid & 3;
    const int lr = l & 15, lk = l >> 4;

    // XCD-aware block decode: 4 N-blocks sharing an A-panel land on one XCD
    const int b = blockIdx.x;
    const int xcd = b & 7, j = b >> 3;
    const int by = j & 3, bx = xcd + 8 * (j >> 2);
    const int bm0 = bx * 256, bn0 = by * 256;

    __shared__ __align__(1024) char tiles[3][2][16384];  // [buf][A=0/B=1]
    __shared__ float rtab[256 * 8];                      // Horner ratios

    // ratio table: r[row][e] = g_e/g_{e+1} (e<7), r[row][7] = g_7
    for (int r = tid; r < 256; r += 512) {
        const float* gr = gvec + (size_t)(bm0 + r) * 8;
        float ge[8];
#pragma unroll
        for (int e = 0; e < 8; ++e) ge[e] = gr[e];
#pragma unroll
        for (int e = 0; e < 7; ++e) rtab[r * 8 + e] = ge[e] / ge[e + 1];
        rtab[r * 8 + 7] = ge[7];
    }
    FENCE();

    // staging: per-tile = 4 loads/thread (2 A + 2 B); dest linear, src pre-swizzled
    const int swz8 = (((l & 3) ^ ((l >> 3) & 3)) << 3);  // element offset in row
    const int rloc = l >> 2;                              // row within 16-row chunk
    auto stageA = [&](int t, int buf) {
        char* base = tiles[buf][0];
        if (t < TE) {
            const ushort_t* src = X + (size_t)bm0 * STRIDEX + (t & (TPE - 1)) * 32 + swz8;
            async_ld16(src + (size_t)(wid * 16 + rloc) * STRIDEX, base + wid * 1024);
            async_ld16(src + (size_t)((wid + 8) * 16 + rloc) * STRIDEX, base + (wid + 8) * 1024);
        } else {
            const ushort_t* src = Gx + (size_t)bm0 * 128 + (t - TE) * 32 + swz8;
            async_ld16(src + (size_t)(wid * 16 + rloc) * 128, base + wid * 1024);
            async_ld16(src + (size_t)((wid + 8) * 16 + rloc) * 128, base + (wid + 8) * 1024);
        }
    };
    auto stageB = [&](int t, int buf) {
        char* base = tiles[buf][1];
        const ushort_t* src = Wt + (size_t)bn0 * Kext + t * 32 + swz8;
        async_ld16(src + (size_t)(wid * 16 + rloc) * Kext, base + wid * 1024);
        async_ld16(src + (size_t)((wid + 8) * 16 + rloc) * Kext, base + (wid + 8) * 1024);
    };

    // swizzled LDS read bases (16B chunk c = lk ^ ((row>>1)&3))
    const int cb = ((lk ^ ((lr >> 1) & 3)) << 4);
    const int arow = (wm * 128 + lr) * 64 + cb;  // + m*1024
    const int brow = (wn * 64 + lr) * 64 + cb;   // + n*1024

    f32x4 acc[8][4];
#pragma unroll
    for (int m = 0; m < 8; ++m)
#pragma unroll
        for (int n = 0; n < 4; ++n) acc[m][n] = zero4();

    // prologue: stage tiles 0,1
    stageA(0, 0); stageB(0, 0);
    stageA(1, 1); stageB(1, 1);

    int cur = 0;
    for (int t = 0; t < NT; ++t) {
        if (t == NT - 1) { asm volatile("s_waitcnt vmcnt(0)" ::: "memory"); }
        else             { asm volatile("s_waitcnt vmcnt(4)" ::: "memory"); }
        BARRIER();  // all waves' tile-t loads landed

        const char* Ap = tiles[cur][0];
        const char* Bp = tiles[cur][1];
        const int sb = cur ? cur - 1 : 2;  // (cur+2)%3: buffer of tile t-1, reads done

        // ---- phase 0: B n0..3 + A m0..3, stage A(t+2), 16 MFMA ----
        bf16x8 bfr[4], afr[4];
#pragma unroll
        for (int n = 0; n < 4; ++n) bfr[n] = *(const bf16x8*)(Bp + brow + n * 1024);
#pragma unroll
        for (int m = 0; m < 4; ++m) afr[m] = *(const bf16x8*)(Ap + arow + m * 1024);
        if (t + 2 < NT) stageA(t + 2, sb);
        BARRIER();
        __builtin_amdgcn_s_setprio(1);
#pragma unroll
        for (int m = 0; m < 4; ++m)
#pragma unroll
            for (int n = 0; n < 4; ++n)
                acc[m][n] = __builtin_amdgcn_mfma_f32_16x16x32_bf16(afr[m], bfr[n], acc[m][n], 0, 0, 0);
        __builtin_amdgcn_s_setprio(0);
        BARRIER();

        // ---- phase 1: A m4..7, stage B(t+2), 16 MFMA ----
#pragma unroll
        for (int m = 0; m < 4; ++m) afr[m] = *(const bf16x8*)(Ap + arow + (m + 4) * 1024);
        if (t + 2 < NT) stageB(t + 2, sb);
        BARRIER();
        __builtin_amdgcn_s_setprio(1);
#pragma unroll
        for (int m = 0; m < 4; ++m)
#pragma unroll
            for (int n = 0; n < 4; ++n)
                acc[m + 4][n] = __builtin_amdgcn_mfma_f32_16x16x32_bf16(afr[m], bfr[n], acc[m + 4][n], 0, 0, 0);
        __builtin_amdgcn_s_setprio(0);
        BARRIER();

        // ---- Horner gate fold at expert boundary ----
        if (t < TE && ((t + 1) & (TPE - 1)) == 0) {
            const int e = t / TPE;
#pragma unroll
            for (int m = 0; m < 8; ++m)
#pragma unroll
                for (int jj = 0; jj < 4; ++jj) {
                    const float r = rtab[(wm * 128 + m * 16 + lk * 4 + jj) * 8 + e];
#pragma unroll
                    for (int n = 0; n < 4; ++n) acc[m][n][jj] *= r;
                }
        }
        cur = (cur == 2) ? 0 : cur + 1;
    }

    // ---- epilogue: relu + bf16 store (bias already folded via K-chunk) ----
#pragma unroll
    for (int m = 0; m < 8; ++m) {
        const int row = bm0 + wm * 128 + m * 16 + lk * 4;
#pragma unroll
        for (int n = 0; n < 4; ++n) {
            const int col = bn0 + wn * 64 + n * 16 + lr;
#pragma unroll
            for (int jj = 0; jj < 4; ++jj) {
                const float v = fmaxf(acc[m][n][jj], 0.f);
                out[(size_t)(row + jj) * N + col] = f2bf(v);
            }
        }
    }
}

// ---------------------------------------------------------------------------
// Legacy fused (MoE-)GEMM — used for gate MLP (ungated) and final L2 layer.
// ---------------------------------------------------------------------------
template <int BN, int TPE, int ACT, bool GATED, bool OUTF32>
__global__ __launch_bounds__(256, 2) void moe_gemm(
    const ushort_t* __restrict__ X, const ushort_t* __restrict__ Wt,
    const float* __restrict__ gvec, const float* __restrict__ bias,
    void* __restrict__ outv, int M, int N, int K) {
    constexpr int BM = 128, BK = 64;
    constexpr int NF = BN / 32;  // n-frags per wave
    const int tid = threadIdx.x;
    const int wid = tid >> 6, lane = tid & 63;
    const int lr = lane & 15, lk = lane >> 4;
    const int bm0 = blockIdx.x * BM;
    const int bn0 = blockIdx.y * BN;
    const int wm0 = (wid >> 1) * 64;
    const int wn0 = (wid & 1) * (BN / 2);

    __shared__ short lds_a[BM * BK];
    __shared__ short lds_b[BN * BK];
    __shared__ float lds_g[BM * 8];
    __shared__ float lds_bias[8 * BN];

    if constexpr (GATED) {
        ((f32x4*)lds_g)[tid] = ((const f32x4*)(gvec + (size_t)bm0 * 8))[tid];
        for (int i = tid; i < 8 * BN; i += 256) {
            const int e = i / BN, n = i - e * BN;
            lds_bias[i] = bias[(size_t)e * N + bn0 + n];
        }
    }

    f32x4 acc_t[4][NF], acc_p[4][NF];
#pragma unroll
    for (int m = 0; m < 4; ++m)
#pragma unroll
        for (int n = 0; n < NF; ++n) { acc_t[m][n] = zero4(); acc_p[m][n] = zero4(); }

    f32x4(&amain)[4][NF] = GATED ? acc_p : acc_t;  // MFMA target

    const int xstride = (TPE > 0) ? TPE * BK : K;  // X row length (elements)
    const int NT = K / BK;
    for (int kt = 0; kt < NT; ++kt) {
        int kcolA;
        if constexpr (TPE > 0) kcolA = (kt % TPE) * BK; else kcolA = kt * BK;
        {
            const ushort_t* abase = X + (size_t)bm0 * xstride + kcolA;
#pragma unroll
            for (int c = wid; c < (BM * BK * 2) / 1024; c += 4) {
                const int off = c * 1024 + lane * 16;
                const int r = off >> 7, cbyte = off & 127;
                async_ld16((const char*)abase + (size_t)r * (xstride * 2) + cbyte,
                           (char*)lds_a + c * 1024);
            }
            const ushort_t* bbase = Wt + (size_t)bn0 * K + kt * BK;
#pragma unroll
            for (int c = wid; c < (BN * BK * 2) / 1024; c += 4) {
                const int off = c * 1024 + lane * 16;
                const int r = off >> 7, cbyte = off & 127;
                async_ld16((const char*)bbase + (size_t)r * ((size_t)K * 2) + cbyte,
                           (char*)lds_b + c * 1024);
            }
        }
        __syncthreads();

        bf16x8 af[2][4], bfr[2][NF];
#pragma unroll
        for (int k2 = 0; k2 < 2; ++k2) {
#pragma unroll
            for (int m = 0; m < 4; ++m)
                af[k2][m] = *(const bf16x8*)&lds_a[(wm0 + m * 16 + lr) * BK + k2 * 32 + lk * 8];
#pragma unroll
            for (int n = 0; n < NF; ++n)
                bfr[k2][n] = *(const bf16x8*)&lds_b[(wn0 + n * 16 + lr) * BK + k2 * 32 + lk * 8];
        }
#pragma unroll
        for (int m = 0; m < 4; ++m)
#pragma unroll
            for (int n = 0; n < NF; ++n) {
                amain[m][n] = __builtin_amdgcn_mfma_f32_16x16x32_bf16(af[0][m], bfr[0][n], amain[m][n], 0, 0, 0);
                amain[m][n] = __builtin_amdgcn_mfma_f32_16x16x32_bf16(af[1][m], bfr[1][n], amain[m][n], 0, 0, 0);
            }

        if constexpr (TPE > 0) {
            if ((kt + 1) % TPE == 0) {
                const int e = kt / TPE;
#pragma unroll
                for (int m = 0; m < 4; ++m)
#pragma unroll
                    for (int jj = 0; jj < 4; ++jj) {
                        const float gw = lds_g[(wm0 + m * 16 + lk * 4 + jj) * 8 + e];
#pragma unroll
                        for (int n = 0; n < NF; ++n) {
                            acc_t[m][n][jj] += gw * acc_p[m][n][jj];
                            acc_p[m][n][jj] = 0.f;
                        }
                    }
            }
        }
        __syncthreads();
    }

#pragma unroll
    for (int m = 0; m < 4; ++m)
#pragma unroll
        for (int n = 0; n < NF; ++n)
#pragma unroll
            for (int jj = 0; jj < 4; ++jj) {
                const int row = wm0 + m * 16 + lk * 4 + jj;
                const int col = wn0 + n * 16 + lr;
                float v = acc_t[m][n][jj];
                if constexpr (GATED) {
                    float bs = 0.f;
#pragma unroll
                    for (int e = 0; e < 8; ++e) bs += lds_g[row * 8 + e] * lds_bias[e * BN + col];
                    v += bs;
                } else {
                    v += bias[bn0 + col];
                }
                if constexpr (ACT == 0) v = fmaxf(v, 0.f);
                else if constexpr (ACT == 1) v = tanhf(v);
                const size_t oidx = (size_t)(bm0 + row) * N + (bn0 + col);
                if constexpr (OUTF32) ((float*)outv)[oidx] = v;
                else ((ushort_t*)outv)[oidx] = f2bf(v);
            }
}

// ---------------------------------------------------------------------------
extern "C" void kernel_launch(void* const* d_in, const int* in_sizes, int n_in,
                              void* d_out, int out_size, void* d_ws, size_t ws_size,
                              hipStream_t stream) {
    const float* inputs = (const float*)d_in[0];
    const float* gw1 = (const float*)d_in[1];
    const float* gb1 = (const float*)d_in[2];
    const float* gw2 = (const float*)d_in[3];
    const float* gb2 = (const float*)d_in[4];
    const float* gw3 = (const float*)d_in[5];
    const float* gb3 = (const float*)d_in[6];
    const float* w0 = (const float*)d_in[7];
    const float* b0 = (const float*)d_in[8];
    const float* w1 = (const float*)d_in[9];
    const float* b1 = (const float*)d_in[10];
    const float* w2 = (const float*)d_in[11];
    const float* b2 = (const float*)d_in[12];
    (void)in_sizes; (void)n_in; (void)out_size; (void)ws_size;

    constexpr int KE0 = NE * DIN + 128;  // 4224
    constexpr int KE1 = NE * H0 + 128;   // 8320

    // workspace layout (region0 reused by x2b after L0 completes)
    char* ws = (char*)d_ws;
    ushort_t* x0b = (ushort_t*)(ws + 0);                 // 16,777,216
    ushort_t* W0t = (ushort_t*)(ws + 16777216);          //  8,650,752  [1024][4224]
    ushort_t* G1t = (ushort_t*)(ws + 25427968);          //    131,072
    ushort_t* G2t = (ushort_t*)(ws + 25559040);          //     32,768
    ushort_t* h1b = (ushort_t*)(ws + 25591808);          //  4,194,304
    ushort_t* h2b = (ushort_t*)(ws + 29786112);          //  4,194,304  (region0 end 33,980,416)
    ushort_t* x2b = (ushort_t*)(ws + 0);                 // 33,554,432 ALIAS of region0
    ushort_t* W1t = (ushort_t*)(ws + 33980416);          // 17,039,360  [1024][8320]
    ushort_t* W2t = (ushort_t*)(ws + 51019776);          //  1,048,576  [64][8192]
    float*    gv  = (float*)(ws + 52068352);             //    524,288
    ushort_t* Gx  = (ushort_t*)(ws + 52592640);          //  4,194,304  [B][128]
    ushort_t* x1b = (ushort_t*)(ws + 56786944);          // 33,554,432

    // convert + transpose weights/inputs to bf16
    f32_to_bf16_vec<<<dim3((BB * DIN) / (256 * 8)), 256, 0, stream>>>(inputs, x0b);
    transpose_convert<<<dim3((NE * DIN) / 64, H0 / 64), 256, 0, stream>>>(w0, W0t, NE * DIN, H0, KE0);
    transpose_convert<<<dim3((NE * H0) / 64, H1 / 64), 256, 0, stream>>>(w1, W1t, NE * H0, H1, KE1);
    transpose_convert<<<dim3((NE * H1) / 64, DOUT / 64), 256, 0, stream>>>(w2, W2t, NE * H1, DOUT, NE * H1);
    transpose_convert<<<dim3(DIN / 64, GH / 64), 256, 0, stream>>>(gw1, G1t, DIN, GH, DIN);
    transpose_convert<<<dim3(GH / 64, GH / 64), 256, 0, stream>>>(gw2, G2t, GH, GH, GH);
    bias_fill<<<dim3(H0), 128, 0, stream>>>(b0, W0t, H0, NE * DIN, KE0);
    bias_fill<<<dim3(H1), 128, 0, stream>>>(b1, W1t, H1, NE * H0, KE1);

    // gate MLP
    moe_gemm<128, 0, 0, false, false><<<dim3(BB / 128, GH / 128), 256, 0, stream>>>(
        x0b, G1t, nullptr, gb1, h1b, BB, GH, DIN);
    moe_gemm<128, 0, 0, false, false><<<dim3(BB / 128, GH / 128), 256, 0, stream>>>(
        h1b, G2t, nullptr, gb2, h2b, BB, GH, GH);
    gate3_softmax<<<dim3(BB / 256), 256, 0, stream>>>(h2b, gw3, gb3, gv, Gx);

    // expert layers 0,1: pipelined 256^2 kernel (gating Horner-folded)
    gemm256<DIN / 32, DIN><<<dim3((BB / 256) * (H0 / 256)), 512, 0, stream>>>(
        x0b, Gx, W0t, gv, x1b, H0, KE0);
    gemm256<H0 / 32, H0><<<dim3((BB / 256) * (H1 / 256)), 512, 0, stream>>>(
        x1b, Gx, W1t, gv, x2b, H1, KE1);

    // expert layer 2 (N=64, tanh, f32 out): legacy kernel
    moe_gemm<64, 16, 1, true, true><<<dim3(BB / 128, DOUT / 64), 256, 0, stream>>>(
        x2b, W2t, gv, b2, d_out, BB, DOUT, NE * H1);
}